// Round 8
// baseline (244.564 us; speedup 1.0000x reference)
//
#include <hip/hip_runtime.h>

// Problem constants
constexpr int BATCH = 4;
constexpr int SEQQ  = 1024;
constexpr int SEQK  = 2048;
constexpr int DIM   = 1024;
constexpr int NH    = 16;
constexpr int DH    = 64;
constexpr int RQ    = BATCH * SEQQ;          // 4096 q rows
constexpr int RK    = BATCH * SEQK;          // 8192 k rows (== v rows)
constexpr int RTOT  = RQ + 2 * RK;           // 20480
constexpr int BH    = BATCH * NH;            // 64
constexpr int NSLC  = 8;                     // s_kernel K-slices
constexpr float LN_EPS = 1e-5f;

typedef _Float16 f16;
typedef __attribute__((ext_vector_type(8))) _Float16 f16x8;
typedef __attribute__((ext_vector_type(4))) float f32x4;

__device__ __forceinline__ void async16(const void* g, void* l) {
  __builtin_amdgcn_global_load_lds(
      (const __attribute__((address_space(1))) void*)g,
      (__attribute__((address_space(3))) void*)l, 16, 0, 0);
}

// ---------------------------------------------------------------------------
// K0: fused {LayerNorm -> fp16} + {W transpose -> fp16} in one launch.
// ---------------------------------------------------------------------------
__global__ void __launch_bounds__(256) pre_kernel(
    const float* __restrict__ q, const float* __restrict__ k,
    const float* __restrict__ v, const float* __restrict__ gamma,
    const float* __restrict__ beta, f16* __restrict__ a_h,
    const float* __restrict__ W0, const float* __restrict__ W1,
    f16* __restrict__ T0, f16* __restrict__ T1) {
  __shared__ float tile[32][33];
  if (blockIdx.x < RTOT / 4) {
    const int row = blockIdx.x * 4 + (threadIdx.x >> 6);
    const int lane = threadIdx.x & 63;
    const float* src;
    if (row < RQ)            src = q + (size_t)row * DIM;
    else if (row < RQ + RK)  src = k + (size_t)(row - RQ) * DIM;
    else                     src = v + (size_t)(row - RQ - RK) * DIM;
    float4 x[4];
    float s = 0.f, s2 = 0.f;
#pragma unroll
    for (int c = 0; c < 4; c++) {
      x[c] = ((const float4*)src)[c * 64 + lane];
      s  += x[c].x + x[c].y + x[c].z + x[c].w;
      s2 += x[c].x * x[c].x + x[c].y * x[c].y + x[c].z * x[c].z + x[c].w * x[c].w;
    }
#pragma unroll
    for (int off = 1; off < 64; off <<= 1) {
      s  += __shfl_xor(s, off);
      s2 += __shfl_xor(s2, off);
    }
    const float mu = s / DIM;
    const float rs = rsqrtf(s2 / DIM - mu * mu + LN_EPS);
#pragma unroll
    for (int c = 0; c < 4; c++) {
      float4 g = ((const float4*)gamma)[c * 64 + lane];
      float4 b = ((const float4*)beta)[c * 64 + lane];
      union { f16 h[4]; uint2 u; } o;
      o.h[0] = (f16)((x[c].x - mu) * rs * g.x + b.x);
      o.h[1] = (f16)((x[c].y - mu) * rs * g.y + b.y);
      o.h[2] = (f16)((x[c].z - mu) * rs * g.z + b.z);
      o.h[3] = (f16)((x[c].w - mu) * rs * g.w + b.w);
      ((uint2*)(a_h + (size_t)row * DIM))[c * 64 + lane] = o.u;
    }
  } else {
    const int tz = blockIdx.x - RTOT / 4;
    const float* W = (tz >= 1024) ? W1 : W0;
    f16* T = (tz >= 1024) ? T1 : T0;
    const int rem = tz & 1023;
    const int k0 = (rem & 31) * 32, n0 = (rem >> 5) * 32;
    int tx = threadIdx.x & 31, ty = threadIdx.x >> 5;
#pragma unroll
    for (int i = 0; i < 4; i++)
      tile[ty + 8 * i][tx] = W[(size_t)(k0 + ty + 8 * i) * DIM + n0 + tx];
    __syncthreads();
#pragma unroll
    for (int i = 0; i < 4; i++)
      T[(size_t)(n0 + ty + 8 * i) * DIM + k0 + tx] = (f16)tile[tx][ty + 8 * i];
  }
}

// ---------------------------------------------------------------------------
// K1: projection GEMM, 320x256 tile -> grid 256 blocks = 1 per CU.
//     ONE barrier per K-tile. (Unchanged from round 7 — verified.)
// ---------------------------------------------------------------------------
constexpr int PT_A = 320 * 64;   // f16 per A tile buffer (20480)
constexpr int PT_B = 256 * 64;   // f16 per B tile buffer (16384)

#define STAGE_A(buf, kt) do {                                        \
    const f16* s_ = gA + (size_t)(kt) * 64;                          \
    f16* d_ = AsW + (buf) * PT_A;                                    \
    async16(s_,          d_);                                        \
    async16(s_ +  65536, d_ + 4096);                                 \
    async16(s_ + 131072, d_ + 8192);                                 \
    async16(s_ + 196608, d_ + 12288);                                \
    async16(s_ + 262144, d_ + 16384);                                \
  } while (0)

#define STAGE_B(buf, kt) do {                                        \
    const f16* s_ = gB + (size_t)(kt) * 64;                          \
    f16* d_ = BsW + (buf) * PT_B;                                    \
    async16(s_,          d_);                                        \
    async16(s_ +  65536, d_ + 4096);                                 \
    async16(s_ + 131072, d_ + 8192);                                 \
    async16(s_ + 196608, d_ + 12288);                                \
  } while (0)

#define STAGE_AB(buf, kt) do { STAGE_A(buf, kt); STAGE_B(buf, kt); } while (0)

#define WT0 asm volatile("s_waitcnt vmcnt(0)" ::: "memory")
#define WTN ((void)0)
#define STN ((void)0)

#define HALF(BUF, H)                                                 \
    _Pragma("unroll") for (int j_ = 0; j_ < 4; ++j_)                 \
      bf[j_] = *(const f16x8*)(bB##H + (BUF) * PT_B + j_ * 1024);    \
    _Pragma("unroll") for (int f_ = 0; f_ < 5; ++f_)                 \
      af0[f_] = *(const f16x8*)(aB##H + (BUF) * PT_A + f_ * 1024);   \
    _Pragma("unroll") for (int f_ = 0; f_ < 5; ++f_)                 \
      af1[f_] = *(const f16x8*)(aB##H + (BUF) * PT_A + 5120 +        \
                                f_ * 1024);                          \
    __builtin_amdgcn_s_setprio(1);                                   \
    _Pragma("unroll") for (int f_ = 0; f_ < 5; ++f_)                 \
      _Pragma("unroll") for (int j_ = 0; j_ < 4; ++j_)               \
        acc[f_][j_] = __builtin_amdgcn_mfma_f32_16x16x32_f16(        \
            af0[f_], bf[j_], acc[f_][j_], 0, 0, 0);                  \
    _Pragma("unroll") for (int f_ = 0; f_ < 5; ++f_)                 \
      _Pragma("unroll") for (int j_ = 0; j_ < 4; ++j_)               \
        acc[5 + f_][j_] = __builtin_amdgcn_mfma_f32_16x16x32_f16(    \
            af1[f_], bf[j_], acc[5 + f_][j_], 0, 0, 0);              \
    __builtin_amdgcn_s_setprio(0);

#define PTILE(BUF, STG, TVW) {                                       \
    __builtin_amdgcn_s_barrier();                                    \
    __builtin_amdgcn_sched_barrier(0);                               \
    STG;                                                             \
    HALF(BUF, 0)                                                     \
    HALF(BUF, 1)                                                     \
    __builtin_amdgcn_sched_barrier(0);                               \
    TVW;                                                             \
  }

__global__ void __launch_bounds__(512, 2) proj_gemm(
    const f16* __restrict__ A, const f16* __restrict__ Bt,
    f16* __restrict__ C) {
  __shared__ __align__(16) f16 As[2 * PT_A];   // 80 KB
  __shared__ __align__(16) f16 Bs[2 * PT_B];   // 64 KB

  const int tid = threadIdx.x;
  const int wid = tid >> 6;
  const int lane = tid & 63;
  const int la15 = lane & 15;

  const int bid = blockIdx.x;
  const int swz = (bid & 7) * 32 + (bid >> 3);
  const int row0 = (swz >> 2) * 320;
  const int col0 = (swz & 3) * 256;

  const int wm = (wid >> 2) * 160;      // warp_m in {0,1}
  const int wn = (wid & 3) * 64;        // warp_n in {0..3}

  const int hs = (tid & 7) ^ ((tid >> 3) & 7);
  const f16* gA = A + (size_t)(row0 + (tid >> 3)) * DIM + (hs >> 2) * 32 +
                  (hs & 3) * 8;
  const f16* gB = Bt + (size_t)(col0 + (tid >> 3)) * DIM + (hs >> 2) * 32 +
                  (hs & 3) * 8;
  f16* AsW = As + wid * 512;            // wave-uniform LDS dest bases
  f16* BsW = Bs + wid * 512;

  const int g = lane >> 4;
  const int r7 = la15 & 7;
  const int cs0 = (g ^ r7) * 8;             // half 0 chunk
  const int cs1 = ((4 + g) ^ r7) * 8;       // half 1 chunk
  const f16* aB0 = As + (wm + la15) * 64 + cs0;
  const f16* aB1 = As + (wm + la15) * 64 + cs1;
  const f16* bB0 = Bs + (wn + la15) * 64 + cs0;
  const f16* bB1 = Bs + (wn + la15) * 64 + cs1;

  f32x4 acc[10][4];
#pragma unroll
  for (int i = 0; i < 10; i++)
#pragma unroll
    for (int j = 0; j < 4; j++) acc[i][j] = (f32x4){0.f, 0.f, 0.f, 0.f};
  f16x8 af0[5], af1[5], bf[4];

  STAGE_AB(0, 0);
  __builtin_amdgcn_sched_barrier(0);
  WT0;

#pragma unroll 1
  for (int it = 0; it < 7; ++it) {
    const int t1 = 2 * it + 1, t2 = 2 * it + 2;
    PTILE(0, STAGE_AB(1, t1), WT0)
    PTILE(1, STAGE_AB(0, t2), WT0)
  }
  PTILE(0, STAGE_AB(1, 15), WT0)
  PTILE(1, STN, WTN)

  // per-head normalization (row predicate: blocks straddle k/v boundary)
  const int crow = (lane >> 4) * 4;
#pragma unroll
  for (int mh = 0; mh < 2; ++mh)
#pragma unroll
    for (int f = 0; f < 5; ++f) {
      const int m = mh * 5 + f;
      const int rbase = row0 + wm + mh * 80 + f * 16 + crow;
#pragma unroll
      for (int r = 0; r < 4; ++r) {
        float s = acc[m][0][r] * acc[m][0][r] + acc[m][1][r] * acc[m][1][r]
                + acc[m][2][r] * acc[m][2][r] + acc[m][3][r] * acc[m][3][r];
        s += __shfl_xor(s, 1);
        s += __shfl_xor(s, 2);
        s += __shfl_xor(s, 4);
        s += __shfl_xor(s, 8);
        if (rbase + r < RQ + RK) {
          const float inv = rsqrtf(s);
#pragma unroll
          for (int j = 0; j < 4; ++j) acc[m][j][r] *= inv;
        }
      }
    }

  // epilogue: LDS-transpose to full-line 16B-contiguous stores
  f16* sc = As;
  const int wmi = wid >> 2;
  const int ehalf = tid >> 8;
  const int err = (tid >> 4) & 15;
  const int ecc = tid & 15;
  const f16* rb_l = sc + ehalf * (16 * 264) + err * 264 + ecc * 16;
#pragma unroll
  for (int mh = 0; mh < 2; ++mh)
#pragma unroll
    for (int f = 0; f < 5; ++f) {
      const int m = mh * 5 + f;
#pragma unroll
      for (int j = 0; j < 4; ++j)
#pragma unroll
        for (int r = 0; r < 4; ++r)
          sc[wmi * (16 * 264) + (crow + r) * 264 + wn + j * 16 + la15] =
              (f16)acc[m][j][r];
      __syncthreads();
      f16x8 v0 = *(const f16x8*)(rb_l);
      f16x8 v1 = *(const f16x8*)(rb_l + 8);
      const int grow = row0 + ehalf * 160 + mh * 80 + f * 16 + err;
      f16* Cp = C + (size_t)grow * DIM + col0 + ecc * 16;
      *(f16x8*)(Cp) = v0;
      *(f16x8*)(Cp + 8) = v1;
      if (!(mh == 1 && f == 4)) __syncthreads();
    }
}

// ---------------------------------------------------------------------------
// K2: per-(slice,b,h) partial St = sum over 256 m of f_v[m] outer g_k[m].
//     Writes TRANSPOSED S (St[d2][d1]) so the attn kernel's B^T operand
//     is directly row-major. (i-inner store keeps 256B-coalescing.)
// ---------------------------------------------------------------------------
__global__ void __launch_bounds__(256) s_kernel(
    const f16* __restrict__ f, float* __restrict__ S4) {
  const int bh = blockIdx.x;
  const int b = bh >> 4, h = bh & 15;
  const int mbase = blockIdx.y * (SEQK / NSLC);
  const int t = threadIdx.x;
  __shared__ float ks[32][68];
  __shared__ float vs[32][68];
  const int lm   = t >> 3;
  const int lseg = (t & 7) * 8;
  const int d1 = (t & 15) * 4;
  const int d2 = (t >> 4) * 4;
  float acc[4][4] = {{0.f}};
  const f16* fk_base = f + ((size_t)RQ + (size_t)b * SEQK) * DIM + h * DH;
  const f16* fv_base = f + ((size_t)RQ + RK + (size_t)b * SEQK) * DIM + h * DH;

  int m = mbase + lm;
  f16x8 kv = *(const f16x8*)(fk_base + (size_t)m * DIM + lseg);
  f16x8 vv = *(const f16x8*)(fv_base + (size_t)m * DIM + lseg);

  constexpr int SUBS = SEQK / NSLC / 32;  // 8
  for (int sub = 0; sub < SUBS; ++sub) {
    __syncthreads();
#pragma unroll
    for (int e = 0; e < 8; e++) {
      ks[lm][lseg + e] = (float)kv[e];
      vs[lm][lseg + e] = (float)vv[e];
    }
    __syncthreads();
    if (sub + 1 < SUBS) {
      m = mbase + (sub + 1) * 32 + lm;
      kv = *(const f16x8*)(fk_base + (size_t)m * DIM + lseg);
      vv = *(const f16x8*)(fv_base + (size_t)m * DIM + lseg);
    }
#pragma unroll
    for (int mm = 0; mm < 32; ++mm) {
      float4 kk = *(const float4*)&ks[mm][d1];
      float4 vv2 = *(const float4*)&vs[mm][d2];
      acc[0][0] = fmaf(kk.x, vv2.x, acc[0][0]);
      acc[0][1] = fmaf(kk.x, vv2.y, acc[0][1]);
      acc[0][2] = fmaf(kk.x, vv2.z, acc[0][2]);
      acc[0][3] = fmaf(kk.x, vv2.w, acc[0][3]);
      acc[1][0] = fmaf(kk.y, vv2.x, acc[1][0]);
      acc[1][1] = fmaf(kk.y, vv2.y, acc[1][1]);
      acc[1][2] = fmaf(kk.y, vv2.z, acc[1][2]);
      acc[1][3] = fmaf(kk.y, vv2.w, acc[1][3]);
      acc[2][0] = fmaf(kk.z, vv2.x, acc[2][0]);
      acc[2][1] = fmaf(kk.z, vv2.y, acc[2][1]);
      acc[2][2] = fmaf(kk.z, vv2.z, acc[2][2]);
      acc[2][3] = fmaf(kk.z, vv2.w, acc[2][3]);
      acc[3][0] = fmaf(kk.w, vv2.x, acc[3][0]);
      acc[3][1] = fmaf(kk.w, vv2.y, acc[3][1]);
      acc[3][2] = fmaf(kk.w, vv2.z, acc[3][2]);
      acc[3][3] = fmaf(kk.w, vv2.w, acc[3][3]);
    }
  }
  // transposed store: St[d2][d1] = acc[i(d1)][j(d2)]
  float* Sp = S4 + ((size_t)blockIdx.y * BH + bh) * DH * DH;
#pragma unroll
  for (int j = 0; j < 4; j++)
#pragma unroll
    for (int i = 0; i < 4; i++)
      Sp[(d2 + j) * DH + (d1 + i)] = acc[i][j];
}

// ---------------------------------------------------------------------------
// K3: attn kernel — per (row-tile, b, h):
//   (1) reduce the NSLC St partials in registers (16 f32/thread),
//   (2) St -> padded LDS f16 [64][72] (2 lanes/bank on bf reads),
//   (3) stage g_q tile (128x64) via async16 + chunk-XOR (proj formula),
//   (4) ao[128x64] = g_q_h @ S_h via MFMA (16 MFMA/wave), f16 out.
// Replaces s_reduce + m_build; out = (g_q S) W_out === g_q (S W_out).
// ---------------------------------------------------------------------------
__global__ void __launch_bounds__(256) attn_kernel(
    const f16* __restrict__ f, const float* __restrict__ S4,
    f16* __restrict__ ao) {
  const int rt = blockIdx.x;            // 0..7 row tile within batch
  const int bh = blockIdx.y;            // 0..63
  const int b = bh >> 4, h = bh & 15;
  const int grow0 = b * SEQQ + rt * 128;
  __shared__ __align__(16) f16 Al[128 * 64];   // 16 KB, XOR-chunked
  __shared__ __align__(16) f16 Bl[64 * 72];    // 9 KB, padded stride 72
  const int tid = threadIdx.x;
  const int wid = tid >> 6;             // 4 waves
  const int lane = tid & 63;
  const int la15 = lane & 15;

  // (3) A stage: wave w rows w*32.., 4 instrs x 8 rows; chunk-XOR source
  const int hsA = (lane & 7) ^ ((lane >> 3) & 7);
  const f16* gq = f + (size_t)(grow0 + wid * 32 + (lane >> 3)) * DIM +
                  h * DH + (hsA >> 2) * 32 + (hsA & 3) * 8;
  f16* lA = Al + wid * 32 * 64;
#pragma unroll
  for (int o = 0; o < 4; o++)
    async16(gq + (size_t)(8 * o) * DIM, lA + 8 * o * 64);

  // (1) reduce partials: thread sums elements [tid*16, tid*16+16)
  const float* Sp = S4 + (size_t)bh * DH * DH + tid * 16;
  constexpr size_t STR = (size_t)BH * DH * DH;
  float4 sv[4];
#pragma unroll
  for (int c = 0; c < 4; c++) sv[c] = (float4){0.f, 0.f, 0.f, 0.f};
#pragma unroll
  for (int p = 0; p < NSLC; p++)
#pragma unroll
    for (int c = 0; c < 4; c++) {
      float4 x = *(const float4*)(Sp + p * STR + 4 * c);
      sv[c].x += x.x; sv[c].y += x.y; sv[c].z += x.z; sv[c].w += x.w;
    }
  // (2) write St f16 to Bl[d2][d1], stride 72
  f16* bw = Bl + (tid >> 2) * 72 + (tid & 3) * 16;
#pragma unroll
  for (int c = 0; c < 4; c++) {
    union { f16 h4[4]; uint2 u; } o;
    o.h4[0] = (f16)sv[c].x; o.h4[1] = (f16)sv[c].y;
    o.h4[2] = (f16)sv[c].z; o.h4[3] = (f16)sv[c].w;
    *(uint2*)(bw + 4 * c) = o.u;
  }
  WT0;                 // drain A-stage DMAs (S4 loads already consumed)
  __syncthreads();

  // (4) MFMA: wave w -> rows wid*32 (2 tiles) x 4 col-tiles, K=64
  const int g2 = lane >> 4;
  f32x4 acc[2][4];
#pragma unroll
  for (int i = 0; i < 2; i++)
#pragma unroll
    for (int j = 0; j < 4; j++) acc[i][j] = (f32x4){0.f, 0.f, 0.f, 0.f};
#pragma unroll
  for (int ks = 0; ks < 2; ks++) {
    f16x8 af[2], bf[4];
#pragma unroll
    for (int i = 0; i < 2; i++) {
      const int row = wid * 32 + i * 16 + la15;
      const int cs = ((ks * 4 + g2) ^ (row & 7)) * 8;
      af[i] = *(const f16x8*)(Al + row * 64 + cs);
    }
#pragma unroll
    for (int j = 0; j < 4; j++)
      bf[j] = *(const f16x8*)(Bl + (j * 16 + la15) * 72 + ks * 32 + g2 * 8);
#pragma unroll
    for (int i = 0; i < 2; i++)
#pragma unroll
      for (int j = 0; j < 4; j++)
        acc[i][j] = __builtin_amdgcn_mfma_f32_16x16x32_f16(
            af[i], bf[j], acc[i][j], 0, 0, 0);
  }

  // C/D layout: col=lane&15, row=(lane>>4)*4+r
  const int crow = (lane >> 4) * 4;
#pragma unroll
  for (int j = 0; j < 4; j++) {
    const int col = h * DH + j * 16 + la15;
#pragma unroll
    for (int i = 0; i < 2; i++) {
      f16* op = ao + (size_t)(grow0 + wid * 32 + i * 16 + crow) * DIM + col;
#pragma unroll
      for (int r = 0; r < 4; r++) op[(size_t)r * DIM] = (f16)acc[i][j][r];
    }
  }
}

// ---------------------------------------------------------------------------
// K4: final GEMM out = attn_out @ W_out + b_out. 128x128 tile, 512 thr,
//     grid 256 = 1/CU. B = wt_out (SHARED across batches -> L2-resident).
// ---------------------------------------------------------------------------
constexpr int FT_SZ = 128 * 64;   // f16 per tile buffer (8192)

#define FSTG(P, gp, kt, buf) do {                                    \
    const f16* s_ = (gp) + (size_t)(kt) * 64;                        \
    f16* d_ = (P) + (buf) * FT_SZ;                                   \
    async16(s_,         d_);                                         \
    async16(s_ + 65536, d_ + 4096);                                  \
  } while (0)

#define FHALF(BUF, H)                                                \
    _Pragma("unroll") for (int j_ = 0; j_ < 2; ++j_)                 \
      gbf[j_] = *(const f16x8*)(bB##H + (BUF) * FT_SZ + j_ * 1024);  \
    _Pragma("unroll") for (int i_ = 0; i_ < 4; ++i_)                 \
      gaf[i_] = *(const f16x8*)(aB##H + (BUF) * FT_SZ + i_ * 1024);  \
    __builtin_amdgcn_s_setprio(1);                                   \
    _Pragma("unroll") for (int i_ = 0; i_ < 4; ++i_)                 \
      _Pragma("unroll") for (int j_ = 0; j_ < 2; ++j_)               \
        facc[i_][j_] = __builtin_amdgcn_mfma_f32_16x16x32_f16(       \
            gaf[i_], gbf[j_], facc[i_][j_], 0, 0, 0);                \
    __builtin_amdgcn_s_setprio(0);

#define FTILE(BUF, STG, TVW) {                                       \
    __builtin_amdgcn_s_barrier();                                    \
    __builtin_amdgcn_sched_barrier(0);                               \
    STG;                                                             \
    FHALF(BUF, 0)                                                    \
    FHALF(BUF, 1)                                                    \
    __builtin_amdgcn_sched_barrier(0);                               \
    TVW;                                                             \
  }

__global__ void __launch_bounds__(512, 2) fin_gemm(
    const f16* __restrict__ ao, const f16* __restrict__ Bt,
    const float* __restrict__ bias, float* __restrict__ out) {
  __shared__ __align__(16) f16 As[2 * FT_SZ];   // 32 KB
  __shared__ __align__(16) f16 Bs[2 * FT_SZ];   // 32 KB
  const int tid = threadIdx.x;
  const int wid = tid >> 6;
  const int lane = tid & 63;
  const int la15 = lane & 15;

  const int bid = blockIdx.x;
  const int swz = (bid & 7) * 32 + (bid >> 3);
  const int rt = swz >> 3;            // 0..31 row tile (global rows)
  const int ct = swz & 7;             // col tile
  const int grow0 = rt * 128;
  const int col0 = ct * 128;

  const int wm = (wid >> 2) * 64;     // warp_m in {0,1}
  const int wn = (wid & 3) * 32;      // warp_n in {0..3}

  const int hs = (tid & 7) ^ ((tid >> 3) & 7);
  const f16* gA = ao + (size_t)(grow0 + (tid >> 3)) * DIM + (hs >> 2) * 32 +
                  (hs & 3) * 8;
  const f16* gB = Bt + (size_t)(col0 + (tid >> 3)) * DIM + (hs >> 2) * 32 +
                  (hs & 3) * 8;
  f16* AsW = As + wid * 512;
  f16* BsW = Bs + wid * 512;

  const int g = lane >> 4;
  const int r7 = la15 & 7;
  const int cs0 = (g ^ r7) * 8;
  const int cs1 = ((4 + g) ^ r7) * 8;
  const f16* aB0 = As + (wm + la15) * 64 + cs0;
  const f16* aB1 = As + (wm + la15) * 64 + cs1;
  const f16* bB0 = Bs + (wn + la15) * 64 + cs0;
  const f16* bB1 = Bs + (wn + la15) * 64 + cs1;

  f32x4 facc[4][2];
#pragma unroll
  for (int i = 0; i < 4; i++)
#pragma unroll
    for (int j = 0; j < 2; j++) facc[i][j] = (f32x4){0.f, 0.f, 0.f, 0.f};
  f16x8 gaf[4], gbf[2];

  FSTG(AsW, gA, 0, 0);
  FSTG(BsW, gB, 0, 0);
  __builtin_amdgcn_sched_barrier(0);
  WT0;

#pragma unroll 1
  for (int it = 0; it < 7; ++it) {
    const int t1 = 2 * it + 1, t2 = 2 * it + 2;
    FTILE(0, { FSTG(AsW, gA, t1, 1); FSTG(BsW, gB, t1, 1); }, WT0)
    FTILE(1, { FSTG(AsW, gA, t2, 0); FSTG(BsW, gB, t2, 0); }, WT0)
  }
  FTILE(0, { FSTG(AsW, gA, 15, 1); FSTG(BsW, gB, 15, 1); }, WT0)
  FTILE(1, STN, WTN)

  const int crow = (lane >> 4) * 4;
#pragma unroll
  for (int j = 0; j < 2; ++j) {
    const int col = col0 + wn + j * 16 + la15;
    const float bv = bias[col];
#pragma unroll
    for (int i = 0; i < 4; ++i) {
      float* Op = out + (size_t)(grow0 + wm + i * 16 + crow) * DIM + col;
#pragma unroll
      for (int r = 0; r < 4; ++r) Op[(size_t)r * DIM] = facc[i][j][r] + bv;
    }
  }
}

// ---------------------------------------------------------------------------
extern "C" void kernel_launch(void* const* d_in, const int* in_sizes, int n_in,
                              void* d_out, int out_size, void* d_ws, size_t ws_size,
                              hipStream_t stream) {
  const float* q     = (const float*)d_in[0];
  const float* k     = (const float*)d_in[1];
  const float* v     = (const float*)d_in[2];
  const float* gamma = (const float*)d_in[3];
  const float* beta  = (const float*)d_in[4];
  const float* W_in  = (const float*)d_in[5];
  const float* W_out = (const float*)d_in[6];
  const float* b_out = (const float*)d_in[7];
  float* out = (float*)d_out;

  // workspace layout
  char* w = (char*)d_ws;
  f16*   f      = (f16*)w;                                     // 40 MB
  f16*   a_h    = f + (size_t)RTOT * DIM;                      // 40 MB
  f16*   wt_in  = a_h + (size_t)RTOT * DIM;                    // 2 MB
  f16*   wt_out = wt_in + (size_t)DIM * DIM;                   // 2 MB
  f16*   ao     = wt_out + (size_t)DIM * DIM;                  // 8 MB (attn_out)
  f16*   Sh     = ao + (size_t)BATCH * DIM * DIM;              // 512 KB (unused)
  float* S4     = (float*)(Sh + (size_t)BH * DH * DH);         // 8 MB

  pre_kernel<<<RTOT / 4 + 2048, 256, 0, stream>>>(
      q, k, v, gamma, beta, a_h, W_in, W_out, wt_in, wt_out);

  // f = LN(t) @ W_in for all rows; q/k rows pre-normalized per head
  proj_gemm<<<dim3(256), 512, 0, stream>>>(a_h, wt_in, f);

  // St partials (transposed S) per (slice, b, h)
  s_kernel<<<dim3(BH, NSLC), 256, 0, stream>>>(f, S4);

  // attn_out = g_q @ S per head (reduces St partials internally)
  attn_kernel<<<dim3(8, BH), 256, 0, stream>>>(f, S4, ao);

  // out = attn_out @ W_out + b_out (shared weights)
  fin_gemm<<<dim3(256), 512, 0, stream>>>(ao, wt_out, b_out, out);
}

// Round 9
// 213.654 us; speedup vs baseline: 1.1447x; 1.1447x over previous
//
#include <hip/hip_runtime.h>

// Problem constants
constexpr int BATCH = 4;
constexpr int SEQQ  = 1024;
constexpr int SEQK  = 2048;
constexpr int DIM   = 1024;
constexpr int NH    = 16;
constexpr int DH    = 64;
constexpr int RQ    = BATCH * SEQQ;          // 4096 q rows
constexpr int RK    = BATCH * SEQK;          // 8192 k rows (== v rows)
constexpr int RTOT  = RQ + 2 * RK;           // 20480
constexpr int BH    = BATCH * NH;            // 64
constexpr int NSLC  = 8;                     // s_kernel K-slices
constexpr float LN_EPS = 1e-5f;

typedef _Float16 f16;
typedef __attribute__((ext_vector_type(8))) _Float16 f16x8;
typedef __attribute__((ext_vector_type(4))) float f32x4;

__device__ __forceinline__ void async16(const void* g, void* l) {
  __builtin_amdgcn_global_load_lds(
      (const __attribute__((address_space(1))) void*)g,
      (__attribute__((address_space(3))) void*)l, 16, 0, 0);
}

// ---------------------------------------------------------------------------
// K0: fused {LayerNorm -> fp16} + {W transpose -> fp16} in one launch.
// ---------------------------------------------------------------------------
__global__ void __launch_bounds__(256) pre_kernel(
    const float* __restrict__ q, const float* __restrict__ k,
    const float* __restrict__ v, const float* __restrict__ gamma,
    const float* __restrict__ beta, f16* __restrict__ a_h,
    const float* __restrict__ W0, const float* __restrict__ W1,
    f16* __restrict__ T0, f16* __restrict__ T1) {
  __shared__ float tile[32][33];
  if (blockIdx.x < RTOT / 4) {
    const int row = blockIdx.x * 4 + (threadIdx.x >> 6);
    const int lane = threadIdx.x & 63;
    const float* src;
    if (row < RQ)            src = q + (size_t)row * DIM;
    else if (row < RQ + RK)  src = k + (size_t)(row - RQ) * DIM;
    else                     src = v + (size_t)(row - RQ - RK) * DIM;
    float4 x[4];
    float s = 0.f, s2 = 0.f;
#pragma unroll
    for (int c = 0; c < 4; c++) {
      x[c] = ((const float4*)src)[c * 64 + lane];
      s  += x[c].x + x[c].y + x[c].z + x[c].w;
      s2 += x[c].x * x[c].x + x[c].y * x[c].y + x[c].z * x[c].z + x[c].w * x[c].w;
    }
#pragma unroll
    for (int off = 1; off < 64; off <<= 1) {
      s  += __shfl_xor(s, off);
      s2 += __shfl_xor(s2, off);
    }
    const float mu = s / DIM;
    const float rs = rsqrtf(s2 / DIM - mu * mu + LN_EPS);
#pragma unroll
    for (int c = 0; c < 4; c++) {
      float4 g = ((const float4*)gamma)[c * 64 + lane];
      float4 b = ((const float4*)beta)[c * 64 + lane];
      union { f16 h[4]; uint2 u; } o;
      o.h[0] = (f16)((x[c].x - mu) * rs * g.x + b.x);
      o.h[1] = (f16)((x[c].y - mu) * rs * g.y + b.y);
      o.h[2] = (f16)((x[c].z - mu) * rs * g.z + b.z);
      o.h[3] = (f16)((x[c].w - mu) * rs * g.w + b.w);
      ((uint2*)(a_h + (size_t)row * DIM))[c * 64 + lane] = o.u;
    }
  } else {
    const int tz = blockIdx.x - RTOT / 4;
    const float* W = (tz >= 1024) ? W1 : W0;
    f16* T = (tz >= 1024) ? T1 : T0;
    const int rem = tz & 1023;
    const int k0 = (rem & 31) * 32, n0 = (rem >> 5) * 32;
    int tx = threadIdx.x & 31, ty = threadIdx.x >> 5;
#pragma unroll
    for (int i = 0; i < 4; i++)
      tile[ty + 8 * i][tx] = W[(size_t)(k0 + ty + 8 * i) * DIM + n0 + tx];
    __syncthreads();
#pragma unroll
    for (int i = 0; i < 4; i++)
      T[(size_t)(n0 + ty + 8 * i) * DIM + k0 + tx] = (f16)tile[tx][ty + 8 * i];
  }
}

// ---------------------------------------------------------------------------
// K1: projection GEMM, 320x256 tile -> grid 256 blocks = 1 per CU.
//     ONE barrier per K-tile. (Unchanged — verified at ~55 us.)
// ---------------------------------------------------------------------------
constexpr int PT_A = 320 * 64;   // f16 per A tile buffer (20480)
constexpr int PT_B = 256 * 64;   // f16 per B tile buffer (16384)

#define STAGE_A(buf, kt) do {                                        \
    const f16* s_ = gA + (size_t)(kt) * 64;                          \
    f16* d_ = AsW + (buf) * PT_A;                                    \
    async16(s_,          d_);                                        \
    async16(s_ +  65536, d_ + 4096);                                 \
    async16(s_ + 131072, d_ + 8192);                                 \
    async16(s_ + 196608, d_ + 12288);                                \
    async16(s_ + 262144, d_ + 16384);                                \
  } while (0)

#define STAGE_B(buf, kt) do {                                        \
    const f16* s_ = gB + (size_t)(kt) * 64;                          \
    f16* d_ = BsW + (buf) * PT_B;                                    \
    async16(s_,          d_);                                        \
    async16(s_ +  65536, d_ + 4096);                                 \
    async16(s_ + 131072, d_ + 8192);                                 \
    async16(s_ + 196608, d_ + 12288);                                \
  } while (0)

#define STAGE_AB(buf, kt) do { STAGE_A(buf, kt); STAGE_B(buf, kt); } while (0)

#define WT0 asm volatile("s_waitcnt vmcnt(0)" ::: "memory")
#define WTN ((void)0)
#define STN ((void)0)

#define HALF(BUF, H)                                                 \
    _Pragma("unroll") for (int j_ = 0; j_ < 4; ++j_)                 \
      bf[j_] = *(const f16x8*)(bB##H + (BUF) * PT_B + j_ * 1024);    \
    _Pragma("unroll") for (int f_ = 0; f_ < 5; ++f_)                 \
      af0[f_] = *(const f16x8*)(aB##H + (BUF) * PT_A + f_ * 1024);   \
    _Pragma("unroll") for (int f_ = 0; f_ < 5; ++f_)                 \
      af1[f_] = *(const f16x8*)(aB##H + (BUF) * PT_A + 5120 +        \
                                f_ * 1024);                          \
    __builtin_amdgcn_s_setprio(1);                                   \
    _Pragma("unroll") for (int f_ = 0; f_ < 5; ++f_)                 \
      _Pragma("unroll") for (int j_ = 0; j_ < 4; ++j_)               \
        acc[f_][j_] = __builtin_amdgcn_mfma_f32_16x16x32_f16(        \
            af0[f_], bf[j_], acc[f_][j_], 0, 0, 0);                  \
    _Pragma("unroll") for (int f_ = 0; f_ < 5; ++f_)                 \
      _Pragma("unroll") for (int j_ = 0; j_ < 4; ++j_)               \
        acc[5 + f_][j_] = __builtin_amdgcn_mfma_f32_16x16x32_f16(    \
            af1[f_], bf[j_], acc[5 + f_][j_], 0, 0, 0);              \
    __builtin_amdgcn_s_setprio(0);

#define PTILE(BUF, STG, TVW) {                                       \
    __builtin_amdgcn_s_barrier();                                    \
    __builtin_amdgcn_sched_barrier(0);                               \
    STG;                                                             \
    HALF(BUF, 0)                                                     \
    HALF(BUF, 1)                                                     \
    __builtin_amdgcn_sched_barrier(0);                               \
    TVW;                                                             \
  }

__global__ void __launch_bounds__(512, 2) proj_gemm(
    const f16* __restrict__ A, const f16* __restrict__ Bt,
    f16* __restrict__ C) {
  __shared__ __align__(16) f16 As[2 * PT_A];   // 80 KB
  __shared__ __align__(16) f16 Bs[2 * PT_B];   // 64 KB

  const int tid = threadIdx.x;
  const int wid = tid >> 6;
  const int lane = tid & 63;
  const int la15 = lane & 15;

  const int bid = blockIdx.x;
  const int swz = (bid & 7) * 32 + (bid >> 3);
  const int row0 = (swz >> 2) * 320;
  const int col0 = (swz & 3) * 256;

  const int wm = (wid >> 2) * 160;      // warp_m in {0,1}
  const int wn = (wid & 3) * 64;        // warp_n in {0..3}

  const int hs = (tid & 7) ^ ((tid >> 3) & 7);
  const f16* gA = A + (size_t)(row0 + (tid >> 3)) * DIM + (hs >> 2) * 32 +
                  (hs & 3) * 8;
  const f16* gB = Bt + (size_t)(col0 + (tid >> 3)) * DIM + (hs >> 2) * 32 +
                  (hs & 3) * 8;
  f16* AsW = As + wid * 512;            // wave-uniform LDS dest bases
  f16* BsW = Bs + wid * 512;

  const int g = lane >> 4;
  const int r7 = la15 & 7;
  const int cs0 = (g ^ r7) * 8;             // half 0 chunk
  const int cs1 = ((4 + g) ^ r7) * 8;       // half 1 chunk
  const f16* aB0 = As + (wm + la15) * 64 + cs0;
  const f16* aB1 = As + (wm + la15) * 64 + cs1;
  const f16* bB0 = Bs + (wn + la15) * 64 + cs0;
  const f16* bB1 = Bs + (wn + la15) * 64 + cs1;

  f32x4 acc[10][4];
#pragma unroll
  for (int i = 0; i < 10; i++)
#pragma unroll
    for (int j = 0; j < 4; j++) acc[i][j] = (f32x4){0.f, 0.f, 0.f, 0.f};
  f16x8 af0[5], af1[5], bf[4];

  STAGE_AB(0, 0);
  __builtin_amdgcn_sched_barrier(0);
  WT0;

#pragma unroll 1
  for (int it = 0; it < 7; ++it) {
    const int t1 = 2 * it + 1, t2 = 2 * it + 2;
    PTILE(0, STAGE_AB(1, t1), WT0)
    PTILE(1, STAGE_AB(0, t2), WT0)
  }
  PTILE(0, STAGE_AB(1, 15), WT0)
  PTILE(1, STN, WTN)

  // per-head normalization (row predicate: blocks straddle k/v boundary)
  const int crow = (lane >> 4) * 4;
#pragma unroll
  for (int mh = 0; mh < 2; ++mh)
#pragma unroll
    for (int f = 0; f < 5; ++f) {
      const int m = mh * 5 + f;
      const int rbase = row0 + wm + mh * 80 + f * 16 + crow;
#pragma unroll
      for (int r = 0; r < 4; ++r) {
        float s = acc[m][0][r] * acc[m][0][r] + acc[m][1][r] * acc[m][1][r]
                + acc[m][2][r] * acc[m][2][r] + acc[m][3][r] * acc[m][3][r];
        s += __shfl_xor(s, 1);
        s += __shfl_xor(s, 2);
        s += __shfl_xor(s, 4);
        s += __shfl_xor(s, 8);
        if (rbase + r < RQ + RK) {
          const float inv = rsqrtf(s);
#pragma unroll
          for (int j = 0; j < 4; ++j) acc[m][j][r] *= inv;
        }
      }
    }

  // epilogue: LDS-transpose to full-line 16B-contiguous stores
  f16* sc = As;
  const int wmi = wid >> 2;
  const int ehalf = tid >> 8;
  const int err = (tid >> 4) & 15;
  const int ecc = tid & 15;
  const f16* rb_l = sc + ehalf * (16 * 264) + err * 264 + ecc * 16;
#pragma unroll
  for (int mh = 0; mh < 2; ++mh)
#pragma unroll
    for (int f = 0; f < 5; ++f) {
      const int m = mh * 5 + f;
#pragma unroll
      for (int j = 0; j < 4; ++j)
#pragma unroll
        for (int r = 0; r < 4; ++r)
          sc[wmi * (16 * 264) + (crow + r) * 264 + wn + j * 16 + la15] =
              (f16)acc[m][j][r];
      __syncthreads();
      f16x8 v0 = *(const f16x8*)(rb_l);
      f16x8 v1 = *(const f16x8*)(rb_l + 8);
      const int grow = row0 + ehalf * 160 + mh * 80 + f * 16 + err;
      f16* Cp = C + (size_t)grow * DIM + col0 + ecc * 16;
      *(f16x8*)(Cp) = v0;
      *(f16x8*)(Cp + 8) = v1;
      if (!(mh == 1 && f == 4)) __syncthreads();
    }
}

// ---------------------------------------------------------------------------
// K2: per-(slice,b,h) partial S = k_h^T @ v_h over 256 m — MFMA version.
//   Per 32-m sub-tile: coalesced f16x8 loads (8 rows x 128B per wave),
//   TRANSPOSED LDS stores kT/vT[64 d][40 m] (stride 40 f16 = 80B keeps
//   b128 reads aligned + 2-way banks; m-chunk XOR swizzle m^=(dc&3)<<3
//   spreads the b16 writes to 2-way), then per wave 1 af + 4 bf b128
//   reads + 4 mfma_f32_16x16x32_f16. Replaces the VALU outer product
//   (512 ds_read_b128/thread -> ~40): LDS-pipe-bound ~20us -> ~8us.
//   Output S4[d1][d2] f32 partials — identical to round-7 interface.
// ---------------------------------------------------------------------------
__global__ void __launch_bounds__(256) s_kernel(
    const f16* __restrict__ f, float* __restrict__ S4) {
  const int bh = blockIdx.x;
  const int b = bh >> 4, h = bh & 15;
  const int mbase = blockIdx.y * (SEQK / NSLC);   // 256 m per slice
  const int tid = threadIdx.x;
  const int wid = tid >> 6, lane = tid & 63;
  const int la15 = lane & 15;

  __shared__ __align__(16) f16 kT[64 * 40];   // 5 KB
  __shared__ __align__(16) f16 vT[64 * 40];   // 5 KB

  // staging thread map: mrow = m within sub-tile, dc8 = 8-f16 d-chunk
  const int mrow = tid >> 3;                  // 0..31
  const int dc8  = tid & 7;                   // 0..7
  const int mw   = mrow ^ ((dc8 & 3) << 3);   // XOR-swizzled m column

  const f16* fk = f + ((size_t)RQ + (size_t)b * SEQK) * DIM + h * DH + dc8 * 8;
  const f16* fv = f + ((size_t)RQ + RK + (size_t)b * SEQK) * DIM + h * DH + dc8 * 8;

  // MFMA fragment read bases (per-thread constants; chunk un-swizzle
  // kc' = kc ^ ((d_row>>3)&3) matches the write-side swizzle)
  const int g2 = lane >> 4;
  const f16* afp = kT + (wid * 16 + la15) * 40 +
                   ((g2 ^ ((wid * 2 + (la15 >> 3)) & 3)) * 8);
  const f16* bfp0 = vT + (0 * 16 + la15) * 40 + ((g2 ^ ((0 + (la15 >> 3)) & 3)) * 8);
  const f16* bfp1 = vT + (1 * 16 + la15) * 40 + ((g2 ^ ((2 + (la15 >> 3)) & 3)) * 8);
  const f16* bfp2 = vT + (2 * 16 + la15) * 40 + ((g2 ^ ((4 + (la15 >> 3)) & 3)) * 8);
  const f16* bfp3 = vT + (3 * 16 + la15) * 40 + ((g2 ^ ((6 + (la15 >> 3)) & 3)) * 8);

  f32x4 acc[4];
#pragma unroll
  for (int j = 0; j < 4; j++) acc[j] = (f32x4){0.f, 0.f, 0.f, 0.f};

  int m = mbase + mrow;
  f16x8 kv = *(const f16x8*)(fk + (size_t)m * DIM);
  f16x8 vv = *(const f16x8*)(fv + (size_t)m * DIM);

  constexpr int SUBS = SEQK / NSLC / 32;  // 8
  for (int sub = 0; sub < SUBS; ++sub) {
    __syncthreads();
#pragma unroll
    for (int e = 0; e < 8; e++) {
      kT[(dc8 * 8 + e) * 40 + mw] = kv[e];
      vT[(dc8 * 8 + e) * 40 + mw] = vv[e];
    }
    __syncthreads();
    if (sub + 1 < SUBS) {
      m = mbase + (sub + 1) * 32 + mrow;
      kv = *(const f16x8*)(fk + (size_t)m * DIM);
      vv = *(const f16x8*)(fv + (size_t)m * DIM);
    }
    f16x8 af = *(const f16x8*)afp;
    acc[0] = __builtin_amdgcn_mfma_f32_16x16x32_f16(af, *(const f16x8*)bfp0, acc[0], 0, 0, 0);
    acc[1] = __builtin_amdgcn_mfma_f32_16x16x32_f16(af, *(const f16x8*)bfp1, acc[1], 0, 0, 0);
    acc[2] = __builtin_amdgcn_mfma_f32_16x16x32_f16(af, *(const f16x8*)bfp2, acc[2], 0, 0, 0);
    acc[3] = __builtin_amdgcn_mfma_f32_16x16x32_f16(af, *(const f16x8*)bfp3, acc[3], 0, 0, 0);
  }

  // C/D layout: col=lane&15 (d2), row=(lane>>4)*4+r (d1 within wave tile)
  float* Sp = S4 + ((size_t)blockIdx.y * BH + bh) * DH * DH;
  const int crow = (lane >> 4) * 4;
#pragma unroll
  for (int j = 0; j < 4; j++)
#pragma unroll
    for (int r = 0; r < 4; r++)
      Sp[(wid * 16 + crow + r) * DH + j * 16 + la15] = acc[j][r];
}

// ---------------------------------------------------------------------------
// K3b: sum the NSLC partial S slices -> Sh fp16 [bh][d1][d2] row-major.
// ---------------------------------------------------------------------------
__global__ void __launch_bounds__(256) s_reduce(
    const float* __restrict__ S4, f16* __restrict__ Sh) {
  const int bh = blockIdx.x;
  const int t = threadIdx.x;
  const size_t base = (size_t)bh * DH * DH + t * 16;
  constexpr size_t STR = (size_t)BH * DH * DH;
#pragma unroll
  for (int c = 0; c < 4; c++) {
    float4 s = {0.f, 0.f, 0.f, 0.f};
#pragma unroll
    for (int p = 0; p < NSLC; p++) {
      float4 sp = *(const float4*)(S4 + base + p * STR + 4 * c);
      s.x += sp.x; s.y += sp.y; s.z += sp.z; s.w += sp.w;
    }
    union { f16 h[4]; uint2 u; } o;
    o.h[0] = (f16)s.x; o.h[1] = (f16)s.y; o.h[2] = (f16)s.z; o.h[3] = (f16)s.w;
    *(uint2*)(Sh + base + 4 * c) = o.u;
  }
}

// ---------------------------------------------------------------------------
// K3c: Mt[b][n][64h+d1] = sum_d2 wt_out[n][64h+d2] * Sh[b,h][d1][d2]
// ---------------------------------------------------------------------------
__global__ void __launch_bounds__(256) m_build(
    const f16* __restrict__ wt_out, const f16* __restrict__ Sh,
    f16* __restrict__ Mt) {
  const int n0 = blockIdx.x * 128;
  const int bh = blockIdx.y;
  const int b = bh >> 4, h = bh & 15;
  __shared__ f16 Asl[128 * 64];
  __shared__ f16 Bsl[64 * 64];
  const int t = threadIdx.x;
  const int wid = t >> 6, lane = t & 63;

  const f16* gA = wt_out + (size_t)(n0 + 32 * wid + (lane >> 3)) * DIM
                  + 64 * h + (lane & 7) * 8;
  f16* lA = Asl + 32 * wid * 64;
  const f16* gB = Sh + (size_t)bh * DH * DH + (16 * wid + (lane >> 3)) * 64
                  + (lane & 7) * 8;
  f16* lB = Bsl + 16 * wid * 64;
#pragma unroll
  for (int o = 0; o < 4; o++) async16(gA + (size_t)(8 * o) * DIM, lA + 8 * o * 64);
  async16(gB, lB);
  async16(gB + 8 * 64, lB + 8 * 64);
  __syncthreads();

  const int wm = (wid >> 1) * 64;
  const int wn = (wid & 1) * 32;
  const int mrow = lane & 15;
  f32x4 acc[4][2];
#pragma unroll
  for (int i = 0; i < 4; i++)
#pragma unroll
    for (int j = 0; j < 2; j++) acc[i][j] = (f32x4){0.f, 0.f, 0.f, 0.f};

#pragma unroll
  for (int kh = 0; kh < 2; kh++) {
    const int kq = kh * 32 + (lane >> 4) * 8;
    f16x8 af[4], bf[2];
#pragma unroll
    for (int i = 0; i < 4; i++)
      af[i] = *(const f16x8*)(Asl + (wm + i * 16 + mrow) * 64 + kq);
#pragma unroll
    for (int j = 0; j < 2; j++)
      bf[j] = *(const f16x8*)(Bsl + (wn + j * 16 + mrow) * 64 + kq);
#pragma unroll
    for (int i = 0; i < 4; i++)
#pragma unroll
      for (int j = 0; j < 2; j++)
        acc[i][j] = __builtin_amdgcn_mfma_f32_16x16x32_f16(af[i], bf[j], acc[i][j], 0, 0, 0);
  }

  const int ccol = lane & 15;
  const int crow = (lane >> 4) * 4;
  f16* Mb = Mt + (size_t)b * DIM * DIM;
#pragma unroll
  for (int j = 0; j < 2; j++) {
    const int col = 64 * h + wn + j * 16 + ccol;
#pragma unroll
    for (int i = 0; i < 4; i++) {
      f16* Mp = Mb + (size_t)(n0 + wm + i * 16 + crow) * DIM + col;
#pragma unroll
      for (int r = 0; r < 4; r++) Mp[(size_t)r * DIM] = (f16)acc[i][j][r];
    }
  }
}

// ---------------------------------------------------------------------------
// K4: final GEMM out = g_q @ Mt[b]^T + b_out. 128x128 tile, 512 thr,
//     grid 256 = 1/CU. (Unchanged from round 7 — verified.)
// ---------------------------------------------------------------------------
constexpr int FT_SZ = 128 * 64;   // f16 per tile buffer (8192)

#define FSTG(P, gp, kt, buf) do {                                    \
    const f16* s_ = (gp) + (size_t)(kt) * 64;                        \
    f16* d_ = (P) + (buf) * FT_SZ;                                   \
    async16(s_,         d_);                                         \
    async16(s_ + 65536, d_ + 4096);                                  \
  } while (0)

#define FHALF(BUF, H)                                                \
    _Pragma("unroll") for (int j_ = 0; j_ < 2; ++j_)                 \
      gbf[j_] = *(const f16x8*)(bB##H + (BUF) * FT_SZ + j_ * 1024);  \
    _Pragma("unroll") for (int i_ = 0; i_ < 4; ++i_)                 \
      gaf[i_] = *(const f16x8*)(aB##H + (BUF) * FT_SZ + i_ * 1024);  \
    __builtin_amdgcn_s_setprio(1);                                   \
    _Pragma("unroll") for (int i_ = 0; i_ < 4; ++i_)                 \
      _Pragma("unroll") for (int j_ = 0; j_ < 2; ++j_)               \
        facc[i_][j_] = __builtin_amdgcn_mfma_f32_16x16x32_f16(       \
            gaf[i_], gbf[j_], facc[i_][j_], 0, 0, 0);                \
    __builtin_amdgcn_s_setprio(0);

#define FTILE(BUF, STG, TVW) {                                       \
    __builtin_amdgcn_s_barrier();                                    \
    __builtin_amdgcn_sched_barrier(0);                               \
    STG;                                                             \
    FHALF(BUF, 0)                                                    \
    FHALF(BUF, 1)                                                    \
    __builtin_amdgcn_sched_barrier(0);                               \
    TVW;                                                             \
  }

__global__ void __launch_bounds__(512, 2) fin_gemm(
    const f16* __restrict__ f, const f16* __restrict__ Mt,
    const float* __restrict__ bias, float* __restrict__ out) {
  __shared__ __align__(16) f16 As[2 * FT_SZ];   // 32 KB
  __shared__ __align__(16) f16 Bs[2 * FT_SZ];   // 32 KB
  const int tid = threadIdx.x;
  const int wid = tid >> 6;
  const int lane = tid & 63;
  const int la15 = lane & 15;

  const int bid = blockIdx.x;
  const int swz = (bid & 7) * 32 + (bid >> 3);
  const int b  = swz >> 6;            // batch
  const int rt = (swz >> 3) & 7;      // row tile within batch
  const int ct = swz & 7;             // col tile
  const int grow0 = b * SEQQ + rt * 128;
  const int col0 = ct * 128;

  const int wm = (wid >> 2) * 64;     // warp_m in {0,1}
  const int wn = (wid & 3) * 32;      // warp_n in {0..3}

  const int hs = (tid & 7) ^ ((tid >> 3) & 7);
  const f16* gA = f + (size_t)(grow0 + (tid >> 3)) * DIM + (hs >> 2) * 32 +
                  (hs & 3) * 8;
  const f16* gB = Mt + (size_t)b * DIM * DIM +
                  (size_t)(col0 + (tid >> 3)) * DIM + (hs >> 2) * 32 +
                  (hs & 3) * 8;
  f16* AsW = As + wid * 512;
  f16* BsW = Bs + wid * 512;

  const int g = lane >> 4;
  const int r7 = la15 & 7;
  const int cs0 = (g ^ r7) * 8;
  const int cs1 = ((4 + g) ^ r7) * 8;
  const f16* aB0 = As + (wm + la15) * 64 + cs0;
  const f16* aB1 = As + (wm + la15) * 64 + cs1;
  const f16* bB0 = Bs + (wn + la15) * 64 + cs0;
  const f16* bB1 = Bs + (wn + la15) * 64 + cs1;

  f32x4 facc[4][2];
#pragma unroll
  for (int i = 0; i < 4; i++)
#pragma unroll
    for (int j = 0; j < 2; j++) facc[i][j] = (f32x4){0.f, 0.f, 0.f, 0.f};
  f16x8 gaf[4], gbf[2];

  FSTG(AsW, gA, 0, 0);
  FSTG(BsW, gB, 0, 0);
  __builtin_amdgcn_sched_barrier(0);
  WT0;

#pragma unroll 1
  for (int it = 0; it < 7; ++it) {
    const int t1 = 2 * it + 1, t2 = 2 * it + 2;
    FTILE(0, { FSTG(AsW, gA, t1, 1); FSTG(BsW, gB, t1, 1); }, WT0)
    FTILE(1, { FSTG(AsW, gA, t2, 0); FSTG(BsW, gB, t2, 0); }, WT0)
  }
  FTILE(0, { FSTG(AsW, gA, 15, 1); FSTG(BsW, gB, 15, 1); }, WT0)
  FTILE(1, STN, WTN)

  const int crow = (lane >> 4) * 4;
#pragma unroll
  for (int j = 0; j < 2; ++j) {
    const int col = col0 + wn + j * 16 + la15;
    const float bv = bias[col];
#pragma unroll
    for (int i = 0; i < 4; ++i) {
      float* Op = out + (size_t)(grow0 + wm + i * 16 + crow) * DIM + col;
#pragma unroll
      for (int r = 0; r < 4; ++r) Op[(size_t)r * DIM] = facc[i][j][r] + bv;
    }
  }
}

// ---------------------------------------------------------------------------
extern "C" void kernel_launch(void* const* d_in, const int* in_sizes, int n_in,
                              void* d_out, int out_size, void* d_ws, size_t ws_size,
                              hipStream_t stream) {
  const float* q     = (const float*)d_in[0];
  const float* k     = (const float*)d_in[1];
  const float* v     = (const float*)d_in[2];
  const float* gamma = (const float*)d_in[3];
  const float* beta  = (const float*)d_in[4];
  const float* W_in  = (const float*)d_in[5];
  const float* W_out = (const float*)d_in[6];
  const float* b_out = (const float*)d_in[7];
  float* out = (float*)d_out;

  // workspace layout
  char* w = (char*)d_ws;
  f16*   f      = (f16*)w;                                     // 40 MB
  f16*   a_h    = f + (size_t)RTOT * DIM;                      // 40 MB
  f16*   wt_in  = a_h + (size_t)RTOT * DIM;                    // 2 MB
  f16*   wt_out = wt_in + (size_t)DIM * DIM;                   // 2 MB
  f16*   Mt     = wt_out + (size_t)DIM * DIM;                  // 8 MB
  f16*   Sh     = Mt + (size_t)BATCH * DIM * DIM;              // 512 KB
  float* S4     = (float*)(Sh + (size_t)BH * DH * DH);         // 8 MB

  pre_kernel<<<RTOT / 4 + 2048, 256, 0, stream>>>(
      q, k, v, gamma, beta, a_h, W_in, W_out, wt_in, wt_out);

  // f = LN(t) @ W_in for all rows; q/k rows pre-normalized per head
  proj_gemm<<<dim3(256), 512, 0, stream>>>(a_h, wt_in, f);

  // S partials per (slice, b, h) via MFMA
  s_kernel<<<dim3(BH, NSLC), 256, 0, stream>>>(f, S4);

  s_reduce<<<BH, 256, 0, stream>>>(S4, Sh);

  m_build<<<dim3(DIM / 128, BH), 256, 0, stream>>>(wt_out, Sh, Mt);

  // out = g_q @ Mt[b]^T + b_out (per-batch weights)
  fin_gemm<<<dim3(256), 512, 0, stream>>>(f, Mt, b_out, out);
}